// Round 1
// baseline (575.624 us; speedup 1.0000x reference)
//
#include <hip/hip_runtime.h>
#include <hip/hip_bf16.h>

typedef __bf16 bf16x8 __attribute__((ext_vector_type(8)));
typedef float f32x4 __attribute__((ext_vector_type(4)));

#define MFMA16(a, b, c) __builtin_amdgcn_mfma_f32_16x16x32_bf16(a, b, c, 0, 0, 0)

static __device__ __forceinline__ unsigned short f2b(float f) {
    __hip_bfloat16 b = __float2bfloat16(f);
    return __builtin_bit_cast(unsigned short, b);
}

// ---------------- weight transpose + bf16 cast: Wt[n][k] = bf16(W[k][n]) ----------------
__global__ void wt_kernel(const float* __restrict__ W0, const float* __restrict__ W1,
                          const float* __restrict__ W2, unsigned short* __restrict__ T0,
                          unsigned short* __restrict__ T1, unsigned short* __restrict__ T2) {
    const float* W = blockIdx.z == 0 ? W0 : (blockIdx.z == 1 ? W1 : W2);
    unsigned short* T = blockIdx.z == 0 ? T0 : (blockIdx.z == 1 ? T1 : T2);
    __shared__ float tile[32][33];
    const int n0 = blockIdx.x * 32, k0 = blockIdx.y * 32;
    const int tx = threadIdx.x, ty = threadIdx.y;  // block (32, 8)
#pragma unroll
    for (int i = 0; i < 4; i++)
        tile[ty + 8 * i][tx] = W[(size_t)(k0 + ty + 8 * i) * 1024 + n0 + tx];
    __syncthreads();
#pragma unroll
    for (int i = 0; i < 4; i++)
        T[(size_t)(n0 + ty + 8 * i) * 1024 + k0 + tx] = f2b(tile[tx][ty + 8 * i]);
}

// ---------------- projection GEMM: dst = bf16(A_f32 @ Wt^T), scattered to head layout ----
// A: [8192][1024] fp32 (converted to bf16 during staging). Wt: [1024 n][1024 k] bf16.
// vmode 0: dst[(b*16+h)*2048 + s][64] (Q,K)   vmode 1: dst[(b*16+h)*64 + d][2048] (V^T)
__global__ __launch_bounds__(256) void proj_kernel(const float* __restrict__ A,
        const unsigned short* __restrict__ Wt, unsigned short* __restrict__ dst,
        const int vmode) {
    __shared__ unsigned short As[128][40];   // +8 pad -> 80B stride (16B-mult), bank-optimal
    __shared__ unsigned short Bs[128][40];
    const int m0 = blockIdx.x * 128, n0 = blockIdx.y * 128;
    const int tid = threadIdx.x;
    const int w = tid >> 6, lane = tid & 63, quad = lane >> 4, l16 = lane & 15;
    const int wr = (w >> 1) * 64, wc = (w & 1) * 64;
    f32x4 acc[4][4] = {};
    for (int kb = 0; kb < 32; kb++) {
        const int k0 = kb * 32;
#pragma unroll
        for (int i = 0; i < 4; i++) {           // A: 128x32 fp32 -> bf16
            int c = tid + i * 256;
            int row = c >> 3, ch = c & 7;
            float4 f = *(const float4*)(A + (size_t)(m0 + row) * 1024 + k0 + ch * 4);
            ushort4 u = { f2b(f.x), f2b(f.y), f2b(f.z), f2b(f.w) };
            *(ushort4*)&As[row][ch * 4] = u;
        }
#pragma unroll
        for (int i = 0; i < 2; i++) {           // B: 128x32 bf16
            int c = tid + i * 256;
            int row = c >> 2, ch = c & 3;
            *(uint4*)&Bs[row][ch * 8] = *(const uint4*)(Wt + (size_t)(n0 + row) * 1024 + k0 + ch * 8);
        }
        __syncthreads();
        bf16x8 af[4], bf[4];
#pragma unroll
        for (int mt = 0; mt < 4; mt++) af[mt] = *(const bf16x8*)&As[wr + mt * 16 + l16][quad * 8];
#pragma unroll
        for (int nt = 0; nt < 4; nt++) bf[nt] = *(const bf16x8*)&Bs[wc + nt * 16 + l16][quad * 8];
#pragma unroll
        for (int mt = 0; mt < 4; mt++)
#pragma unroll
            for (int nt = 0; nt < 4; nt++)
                acc[mt][nt] = MFMA16(af[mt], bf[nt], acc[mt][nt]);
        __syncthreads();
    }
#pragma unroll
    for (int mt = 0; mt < 4; mt++)
#pragma unroll
        for (int nt = 0; nt < 4; nt++)
#pragma unroll
            for (int r = 0; r < 4; r++) {
                int gr = m0 + wr + mt * 16 + quad * 4 + r;   // token
                int gc = n0 + wc + nt * 16 + l16;            // out channel
                int b = gr >> 11, s = gr & 2047, h = gc >> 6, d = gc & 63;
                size_t idx = vmode ? (((size_t)(b * 16 + h) * 64 + d) * 2048 + s)
                                   : (((size_t)(b * 16 + h) * 2048 + s) * 64 + d);
                dst[idx] = f2b(acc[mt][nt][r]);
            }
}

// ---------------- fused masked-causal flash attention ----------------
// Qp,Kp: [bh][2048][64] bf16.  Vt: [bh][64][2048] bf16.  out: [b][s][1024] fp32.
// Full kv range (matches reference's fp32 -1e10 additive-mask softmax exactly);
// fully-future tiles skip QK^T (scores are mask-only by fp32 absorption) and skip
// PV unless the wave holds a degenerate (all-prefix-masked) row.
__global__ __launch_bounds__(256) void attn_kernel(
        const unsigned short* __restrict__ Qp, const unsigned short* __restrict__ Kp,
        const unsigned short* __restrict__ Vt, const float* __restrict__ vmask,
        const float* __restrict__ qmask, float* __restrict__ out) {
    __shared__ unsigned short Ks[64][72];    // K tile  [kv][d],  +8 pad
    __shared__ unsigned short Vts[64][72];   // V^T tile [d][kv], +8 pad
    __shared__ unsigned short Ps[128][72];   // P tile  [q][kv] (wave-private rows)
    const int qt = blockIdx.x, bh = blockIdx.y;
    const int b = bh >> 4, h = bh & 15;
    const int q0 = qt * 128;
    const int tid = threadIdx.x;
    const int w = tid >> 6, lane = tid & 63, quad = lane >> 4, l16 = lane & 15;
    const size_t base = (size_t)bh * 2048 * 64;

    bf16x8 qa[2][2];                         // Q A-fragments, resident in registers
#pragma unroll
    for (int mt = 0; mt < 2; mt++)
#pragma unroll
        for (int ks = 0; ks < 2; ks++)
            qa[mt][ks] = *(const bf16x8*)(Qp + base +
                (size_t)(q0 + w * 32 + mt * 16 + l16) * 64 + ks * 32 + quad * 8);

    f32x4 o[2][4] = {};
    float m_run[2][4], l_run[2][4];
#pragma unroll
    for (int mt = 0; mt < 2; mt++)
#pragma unroll
        for (int r = 0; r < 4; r++) { m_run[mt][r] = -1e30f; l_run[mt][r] = 0.f; }

    const int kdiag = 2 * qt + 2;            // tiles >= kdiag are fully beyond-causal
    for (int kt = 0; kt < 32; kt++) {
        if (kt) __syncthreads();
        const bool future = (kt >= kdiag);
#pragma unroll
        for (int i = 0; i < 2; i++) {        // stage tiles
            int c = tid + i * 256;
            int row = c >> 3, ch = c & 7;
            *(uint4*)&Vts[row][ch * 8] = *(const uint4*)(Vt + base + (size_t)row * 2048 + kt * 64 + ch * 8);
            if (!future)
                *(uint4*)&Ks[row][ch * 8] = *(const uint4*)(Kp + base + (size_t)(kt * 64 + row) * 64 + ch * 8);
        }
        __syncthreads();

        if (future) {                        // wave-level skip if no degenerate rows
            bool deg = false;
#pragma unroll
            for (int mt = 0; mt < 2; mt++)
#pragma unroll
                for (int r = 0; r < 4; r++) deg |= (m_run[mt][r] < -5e9f);
            if (!__any((int)deg)) continue;  // all threads still hit both loop barriers
        }

        f32x4 s[2][4];
        if (!future) {                       // S = Q K^T
#pragma unroll
            for (int nt = 0; nt < 4; nt++) {
                bf16x8 kf0 = *(const bf16x8*)&Ks[nt * 16 + l16][quad * 8];
                bf16x8 kf1 = *(const bf16x8*)&Ks[nt * 16 + l16][32 + quad * 8];
#pragma unroll
                for (int mt = 0; mt < 2; mt++) {
                    f32x4 z = {};
                    z = MFMA16(qa[mt][0], kf0, z);
                    z = MFMA16(qa[mt][1], kf1, z);
                    s[mt][nt] = z;
                }
            }
        }

        float tmax[2][4];
#pragma unroll
        for (int mt = 0; mt < 2; mt++)
#pragma unroll
            for (int r = 0; r < 4; r++) tmax[mt][r] = -1e30f;
        float pv[2][4][4];
#pragma unroll
        for (int nt = 0; nt < 4; nt++) {
            const int kv = kt * 64 + nt * 16 + l16;
            const float bias = (vmask[b * 2048 + kv] - 1.0f) * 1e10f;
#pragma unroll
            for (int mt = 0; mt < 2; mt++) {
                const int qrow = q0 + w * 32 + mt * 16 + quad * 4;
#pragma unroll
                for (int r = 0; r < 4; r++) {
                    float sv = future ? (bias - 1e10f)
                                      : (s[mt][nt][r] * 0.125f + bias - ((kv > qrow + r) ? 1e10f : 0.f));
                    pv[mt][nt][r] = sv;
                    tmax[mt][r] = fmaxf(tmax[mt][r], sv);
                }
            }
        }
#pragma unroll
        for (int mt = 0; mt < 2; mt++)       // row max across the 16 col-lanes
#pragma unroll
            for (int r = 0; r < 4; r++) {
                float t = tmax[mt][r];
#pragma unroll
                for (int off = 1; off < 16; off <<= 1) t = fmaxf(t, __shfl_xor(t, off));
                float mn = fmaxf(m_run[mt][r], t);
                float al = exp2f((m_run[mt][r] - mn) * 1.44269504f);
                m_run[mt][r] = mn;
                tmax[mt][r] = al;            // reuse as alpha
            }
        float rs[2][4] = {};
#pragma unroll
        for (int nt = 0; nt < 4; nt++)
#pragma unroll
            for (int mt = 0; mt < 2; mt++)
#pragma unroll
                for (int r = 0; r < 4; r++) {
                    float e = exp2f((pv[mt][nt][r] - m_run[mt][r]) * 1.44269504f);
                    pv[mt][nt][r] = e;
                    rs[mt][r] += e;
                }
#pragma unroll
        for (int mt = 0; mt < 2; mt++)
#pragma unroll
            for (int r = 0; r < 4; r++) {
                float t = rs[mt][r];
#pragma unroll
                for (int off = 1; off < 16; off <<= 1) t += __shfl_xor(t, off);
                l_run[mt][r] = l_run[mt][r] * tmax[mt][r] + t;
            }
#pragma unroll
        for (int mt = 0; mt < 2; mt++)       // rescale O by alpha
#pragma unroll
            for (int dt = 0; dt < 4; dt++)
#pragma unroll
                for (int r = 0; r < 4; r++) o[mt][dt][r] *= tmax[mt][r];
#pragma unroll
        for (int mt = 0; mt < 2; mt++)       // P -> LDS (C-layout -> A-layout transform)
#pragma unroll
            for (int nt = 0; nt < 4; nt++)
#pragma unroll
                for (int r = 0; r < 4; r++)
                    Ps[w * 32 + mt * 16 + quad * 4 + r][nt * 16 + l16] = f2b(pv[mt][nt][r]);
        // O += P V  (wave-private P rows; in-wave LDS ordering, no barrier needed)
#pragma unroll
        for (int k2 = 0; k2 < 2; k2++) {
            bf16x8 pa[2];
#pragma unroll
            for (int mt = 0; mt < 2; mt++)
                pa[mt] = *(const bf16x8*)&Ps[w * 32 + mt * 16 + l16][k2 * 32 + quad * 8];
#pragma unroll
            for (int dt = 0; dt < 4; dt++) {
                bf16x8 vb = *(const bf16x8*)&Vts[dt * 16 + l16][k2 * 32 + quad * 8];
#pragma unroll
                for (int mt = 0; mt < 2; mt++)
                    o[mt][dt] = MFMA16(pa[mt], vb, o[mt][dt]);
            }
        }
    }
#pragma unroll
    for (int mt = 0; mt < 2; mt++)
#pragma unroll
        for (int r = 0; r < 4; r++) {
            int q = q0 + w * 32 + mt * 16 + quad * 4 + r;
            float sc = qmask[b * 2048 + q] / l_run[mt][r];
#pragma unroll
            for (int dt = 0; dt < 4; dt++)
                out[(size_t)(b * 2048 + q) * 1024 + h * 64 + dt * 16 + l16] = o[mt][dt][r] * sc;
        }
}

extern "C" void kernel_launch(void* const* d_in, const int* in_sizes, int n_in,
                              void* d_out, int out_size, void* d_ws, size_t ws_size,
                              hipStream_t stream) {
    const float* q  = (const float*)d_in[0];
    const float* k  = (const float*)d_in[1];
    const float* v  = (const float*)d_in[2];
    const float* vm = (const float*)d_in[3];
    const float* qm = (const float*)d_in[4];
    const float* Wq = (const float*)d_in[5];
    const float* Wk = (const float*)d_in[6];
    const float* Wv = (const float*)d_in[7];
    float* out = (float*)d_out;

    unsigned short* ws  = (unsigned short*)d_ws;
    unsigned short* Wtq = ws;                         // 3 x 1M bf16 (transposed weights)
    unsigned short* Wtk = Wtq + (1u << 20);
    unsigned short* Wtv = Wtk + (1u << 20);
    unsigned short* Qp  = Wtv + (1u << 20);           // 3 x 8M bf16 (projected Q, K, V^T)
    unsigned short* Kp  = Qp + (1u << 23);
    unsigned short* Vtp = Kp + (1u << 23);

    wt_kernel<<<dim3(32, 32, 3), dim3(32, 8), 0, stream>>>(Wq, Wk, Wv, Wtq, Wtk, Wtv);
    proj_kernel<<<dim3(64, 8), 256, 0, stream>>>(q, Wtq, Qp, 0);
    proj_kernel<<<dim3(64, 8), 256, 0, stream>>>(k, Wtk, Kp, 0);
    proj_kernel<<<dim3(64, 8), 256, 0, stream>>>(v, Wtv, Vtp, 1);
    attn_kernel<<<dim3(16, 64), 256, 0, stream>>>(Qp, Kp, Vtp, vm, qm, out);
}

// Round 2
// 366.137 us; speedup vs baseline: 1.5722x; 1.5722x over previous
//
#include <hip/hip_runtime.h>
#include <hip/hip_bf16.h>

typedef __bf16 bf16x8 __attribute__((ext_vector_type(8)));
typedef float f32x4 __attribute__((ext_vector_type(4)));
typedef unsigned int u32;

#define MFMA16(a, b, c) __builtin_amdgcn_mfma_f32_16x16x32_bf16(a, b, c, 0, 0, 0)

static __device__ __forceinline__ unsigned short f2b(float f) {
    __hip_bfloat16 b = __float2bfloat16(f);
    return __builtin_bit_cast(unsigned short, b);
}
static __device__ __forceinline__ float b2f(unsigned short u) {
    u32 v = ((u32)u) << 16;
    return __builtin_bit_cast(float, v);
}
static __device__ __forceinline__ void glds16(const void* g, void* l) {
    __builtin_amdgcn_global_load_lds((const __attribute__((address_space(1))) u32*)g,
                                     (__attribute__((address_space(3))) u32*)l, 16, 0, 0);
}

// ---------------- fp32 -> bf16 convert (activations), 8 elems/thread ----------------
__global__ __launch_bounds__(256) void cvt_kernel(const float* __restrict__ src,
                                                  unsigned short* __restrict__ dst) {
    const size_t i = ((size_t)blockIdx.x * 256 + threadIdx.x) * 8;
    float4 a = *(const float4*)(src + i);
    float4 b = *(const float4*)(src + i + 4);
    ushort4 u0 = { f2b(a.x), f2b(a.y), f2b(a.z), f2b(a.w) };
    ushort4 u1 = { f2b(b.x), f2b(b.y), f2b(b.z), f2b(b.w) };
    *(ushort4*)(dst + i) = u0;
    *(ushort4*)(dst + i + 4) = u1;
}

// ---------------- weight transpose + bf16 cast: Wt[n][k] = bf16(W[k][n]) ----------------
__global__ void wt_kernel(const float* __restrict__ W0, const float* __restrict__ W1,
                          const float* __restrict__ W2, unsigned short* __restrict__ T0,
                          unsigned short* __restrict__ T1, unsigned short* __restrict__ T2) {
    const float* W = blockIdx.z == 0 ? W0 : (blockIdx.z == 1 ? W1 : W2);
    unsigned short* T = blockIdx.z == 0 ? T0 : (blockIdx.z == 1 ? T1 : T2);
    __shared__ float tile[32][33];
    const int n0 = blockIdx.x * 32, k0 = blockIdx.y * 32;
    const int tx = threadIdx.x, ty = threadIdx.y;  // block (32, 8)
#pragma unroll
    for (int i = 0; i < 4; i++)
        tile[ty + 8 * i][tx] = W[(size_t)(k0 + ty + 8 * i) * 1024 + n0 + tx];
    __syncthreads();
#pragma unroll
    for (int i = 0; i < 4; i++)
        T[(size_t)(n0 + ty + 8 * i) * 1024 + k0 + tx] = f2b(tile[tx][ty + 8 * i]);
}

// ---------------- projection GEMM (m97-style): dst = bf16(A @ Wt^T) -------------------
// A: [8192][1024] bf16.  Wt: [1024 n][1024 k] bf16.
// vmode 0: dst[(b*16+h)*2048 + s][64] (Q,K)   vmode 1: dst[(b*16+h)*64 + d][2048] (V^T)
__global__ __launch_bounds__(256) void proj_kernel(const unsigned short* __restrict__ A,
        const unsigned short* __restrict__ Wt, unsigned short* __restrict__ dst,
        const int vmode) {
    __shared__ unsigned short smem[18432];   // staging: As=smem[0:4096), Bs=[4096:8192)
    unsigned short* As = smem;               // [128][32] unpadded (global_load_lds layout)
    unsigned short* Bs = smem + 4096;
    const int m0 = blockIdx.x * 128, n0 = blockIdx.y * 128;
    const int tid = threadIdx.x;
    const int w = tid >> 6, lane = tid & 63, quad = lane >> 4, l16 = lane & 15;
    const int wr = (w >> 1) * 64, wc = (w & 1) * 64;
    f32x4 acc[4][4] = {};
    for (int kb = 0; kb < 32; kb++) {
        const int k0 = kb * 32;
        __syncthreads();
#pragma unroll
        for (int i = 0; i < 2; i++) {        // 16B/lane direct-to-LDS DMA
            int idx = tid + i * 256;         // [0,512): row=idx>>2, col8=(idx&3)*8
            int row = idx >> 2, col = (idx & 3) * 8;
            glds16(A + (size_t)(m0 + row) * 1024 + k0 + col, &As[idx * 8]);
            glds16(Wt + (size_t)(n0 + row) * 1024 + k0 + col, &Bs[idx * 8]);
        }
        __syncthreads();
        bf16x8 af[4], bf[4];
#pragma unroll
        for (int mt = 0; mt < 4; mt++) af[mt] = *(const bf16x8*)&As[(wr + mt * 16 + l16) * 32 + quad * 8];
#pragma unroll
        for (int nt = 0; nt < 4; nt++) bf[nt] = *(const bf16x8*)&Bs[(wc + nt * 16 + l16) * 32 + quad * 8];
#pragma unroll
        for (int mt = 0; mt < 4; mt++)
#pragma unroll
            for (int nt = 0; nt < 4; nt++)
                acc[mt][nt] = MFMA16(af[mt], bf[nt], acc[mt][nt]);
    }
    __syncthreads();
    if (vmode == 0) {                        // Q,K: scatter in 32B runs
#pragma unroll
        for (int mt = 0; mt < 4; mt++)
#pragma unroll
            for (int nt = 0; nt < 4; nt++)
#pragma unroll
                for (int r = 0; r < 4; r++) {
                    int gr = m0 + wr + mt * 16 + quad * 4 + r;   // token
                    int gc = n0 + wc + nt * 16 + l16;            // out channel
                    int b = gr >> 11, s = gr & 2047, h = gc >> 6, d = gc & 63;
                    dst[((size_t)(b * 16 + h) * 2048 + s) * 64 + d] = f2b(acc[mt][nt][r]);
                }
    } else {                                 // V^T: LDS transpose -> coalesced stores
        unsigned short* Tw = smem + w * 4608;          // per-wave 64x72
#pragma unroll
        for (int mt = 0; mt < 4; mt++)
#pragma unroll
            for (int nt = 0; nt < 4; nt++)
#pragma unroll
                for (int r = 0; r < 4; r++)
                    Tw[(nt * 16 + l16) * 72 + mt * 16 + quad * 4 + r] = f2b(acc[mt][nt][r]);
        const int gr0 = m0 + wr, gc0 = n0 + wc;
        const int b = gr0 >> 11, s0 = gr0 & 2047, h = gc0 >> 6;
        const size_t vbase = ((size_t)(b * 16 + h) * 64) * 2048;
        // wave-private buffer, in-wave LDS ordering -> no barrier needed
#pragma unroll
        for (int j = 0; j < 16; j++) {
            int n = j * 4 + quad, m = l16 * 4;
            uint2 val = *(const uint2*)&Tw[n * 72 + m];
            *(uint2*)(dst + vbase + (size_t)n * 2048 + s0 + m) = val;
        }
    }
}

// ---------------- fused masked-causal flash attention ----------------
// Qp,Kp: [bh][2048][64] bf16.  Vt: [bh][64][2048] bf16.  out: [b][s][1024] fp32.
// Fixed-max softmax e^(s-8) (masked entries underflow to exact 0, matching the
// reference's fp32 -1e10 absorption). Degenerate rows (all-prefix-masked, l==0)
// get the reference's uniform average via a rare fix-up pass over global V.
// Each block processes q-tiles {x, 15-x}: uniform 34 kv-tile iterations.
__global__ __launch_bounds__(256) void attn_kernel(
        const unsigned short* __restrict__ Qp, const unsigned short* __restrict__ Kp,
        const unsigned short* __restrict__ Vt, const float* __restrict__ vmask,
        const float* __restrict__ qmask, float* __restrict__ out) {
    __shared__ unsigned short Ks[64][72];    // K tile  [kv][d],  +8 pad
    __shared__ unsigned short Vts[64][72];   // V^T tile [d][kv], +8 pad
    __shared__ unsigned short Ps[128][72];   // P tile  [q][kv] (wave-private rows)
    const int bh = blockIdx.y, b = bh >> 4, h = bh & 15;
    const int tid = threadIdx.x;
    const int w = tid >> 6, lane = tid & 63, quad = lane >> 4, l16 = lane & 15;
    const size_t base = (size_t)bh * 2048 * 64;
    const float C1 = 0.18033688f;            // 0.125 * log2(e)
    const float CM = -1.44269504e10f;        // -1e10 * log2(e)
    const float C0 = -11.54156036f;          // -8 * log2(e)

    for (int pass = 0; pass < 2; pass++) {
        const int qt = pass ? 15 - blockIdx.x : blockIdx.x;
        const int q0 = qt * 128;
        bf16x8 qa[2][2];
#pragma unroll
        for (int mt = 0; mt < 2; mt++)
#pragma unroll
            for (int ks = 0; ks < 2; ks++)
                qa[mt][ks] = *(const bf16x8*)(Qp + base +
                    (size_t)(q0 + w * 32 + mt * 16 + l16) * 64 + ks * 32 + quad * 8);
        f32x4 o[2][4] = {};
        float lsum[2][4] = {};

        const int kdiag = 2 * qt + 2;
        for (int kt = 0; kt < kdiag; kt++) {
            __syncthreads();                 // protect LDS reuse (prev iter / prev pass)
#pragma unroll
            for (int i = 0; i < 2; i++) {
                int c = tid + i * 256;
                int row = c >> 3, ch = c & 7;
                *(uint4*)&Vts[row][ch * 8] = *(const uint4*)(Vt + base + (size_t)row * 2048 + kt * 64 + ch * 8);
                *(uint4*)&Ks[row][ch * 8]  = *(const uint4*)(Kp + base + (size_t)(kt * 64 + row) * 64 + ch * 8);
            }
            __syncthreads();

            f32x4 s[2][4];                   // S = Q K^T
#pragma unroll
            for (int nt = 0; nt < 4; nt++) {
                bf16x8 kf0 = *(const bf16x8*)&Ks[nt * 16 + l16][quad * 8];
                bf16x8 kf1 = *(const bf16x8*)&Ks[nt * 16 + l16][32 + quad * 8];
#pragma unroll
                for (int mt = 0; mt < 2; mt++) {
                    f32x4 z = {};
                    z = MFMA16(qa[mt][0], kf0, z);
                    z = MFMA16(qa[mt][1], kf1, z);
                    s[mt][nt] = z;
                }
            }
            // p = e^(s/8 + bias - 8); accumulate l; P -> LDS (C-layout -> A-layout)
#pragma unroll
            for (int nt = 0; nt < 4; nt++) {
                const int kv = kt * 64 + nt * 16 + l16;
                const float cb = (vmask[b * 2048 + kv] != 0.f) ? C0 : (CM + C0);
#pragma unroll
                for (int mt = 0; mt < 2; mt++) {
                    const int qrow = q0 + w * 32 + mt * 16 + quad * 4;
#pragma unroll
                    for (int r = 0; r < 4; r++) {
                        float ex = s[mt][nt][r] * C1 + cb + ((kv > qrow + r) ? CM : 0.f);
                        float p = exp2f(ex);
                        lsum[mt][r] += p;
                        Ps[w * 32 + mt * 16 + quad * 4 + r][nt * 16 + l16] = f2b(p);
                    }
                }
            }
            // O += P V  (wave-private P rows; in-wave LDS ordering, no barrier)
#pragma unroll
            for (int k2 = 0; k2 < 2; k2++) {
                bf16x8 pa[2];
#pragma unroll
                for (int mt = 0; mt < 2; mt++)
                    pa[mt] = *(const bf16x8*)&Ps[w * 32 + mt * 16 + l16][k2 * 32 + quad * 8];
#pragma unroll
                for (int dt = 0; dt < 4; dt++) {
                    bf16x8 vb = *(const bf16x8*)&Vts[dt * 16 + l16][k2 * 32 + quad * 8];
#pragma unroll
                    for (int mt = 0; mt < 2; mt++)
                        o[mt][dt] = MFMA16(pa[mt], vb, o[mt][dt]);
                }
            }
        }
        // single deferred l reduction across the 16 column-lanes
        float l[2][4];
#pragma unroll
        for (int mt = 0; mt < 2; mt++)
#pragma unroll
            for (int r = 0; r < 4; r++) {
                float t = lsum[mt][r];
#pragma unroll
                for (int off = 1; off < 16; off <<= 1) t += __shfl_xor(t, off);
                l[mt][r] = t;
            }
        // degenerate rows (entire causal prefix v-masked): reference semantics =
        // uniform average over {kv <= q} u {kv > q : vmask==1}
        bool deg = false;
#pragma unroll
        for (int mt = 0; mt < 2; mt++)
#pragma unroll
            for (int r = 0; r < 4; r++) deg |= (l[mt][r] == 0.f);
        if (__any((int)deg)) {
#pragma unroll
            for (int mt = 0; mt < 2; mt++)
#pragma unroll
                for (int r = 0; r < 4; r++)
                    if (l[mt][r] == 0.f) {
                        const int qrow = q0 + w * 32 + mt * 16 + quad * 4 + r;
                        float cnt = 0.f;
                        float oacc[4] = {0.f, 0.f, 0.f, 0.f};
                        for (int kv = 0; kv < 2048; kv++) {
                            bool keep = (kv <= qrow) || (vmask[b * 2048 + kv] != 0.f);
                            if (keep) {
                                cnt += 1.f;
#pragma unroll
                                for (int dt = 0; dt < 4; dt++)
                                    oacc[dt] += b2f(Vt[base + (size_t)(dt * 16 + l16) * 2048 + kv]);
                            }
                        }
                        l[mt][r] = cnt;
#pragma unroll
                        for (int dt = 0; dt < 4; dt++) o[mt][dt][r] = oacc[dt];
                    }
        }
#pragma unroll
        for (int mt = 0; mt < 2; mt++)
#pragma unroll
            for (int r = 0; r < 4; r++) {
                int q = q0 + w * 32 + mt * 16 + quad * 4 + r;
                float sc = qmask[b * 2048 + q] / l[mt][r];
#pragma unroll
                for (int dt = 0; dt < 4; dt++)
                    out[(size_t)(b * 2048 + q) * 1024 + h * 64 + dt * 16 + l16] = o[mt][dt][r] * sc;
            }
    }
}

extern "C" void kernel_launch(void* const* d_in, const int* in_sizes, int n_in,
                              void* d_out, int out_size, void* d_ws, size_t ws_size,
                              hipStream_t stream) {
    const float* q  = (const float*)d_in[0];
    const float* k  = (const float*)d_in[1];
    const float* v  = (const float*)d_in[2];
    const float* vm = (const float*)d_in[3];
    const float* qm = (const float*)d_in[4];
    const float* Wq = (const float*)d_in[5];
    const float* Wk = (const float*)d_in[6];
    const float* Wv = (const float*)d_in[7];
    float* out = (float*)d_out;

    unsigned short* ws  = (unsigned short*)d_ws;
    unsigned short* Wtq = ws;                         // 3 x 1M bf16 (transposed weights)
    unsigned short* Wtk = Wtq + (1u << 20);
    unsigned short* Wtv = Wtk + (1u << 20);
    unsigned short* Qp  = Wtv + (1u << 20);           // 3 x 8M bf16 (projected Q, K, V^T)
    unsigned short* Kp  = Qp + (1u << 23);
    unsigned short* Vtp = Kp + (1u << 23);
    // reuse d_out (32 MB fp32) as the 16 MB bf16 activation-conversion scratch;
    // attn fully overwrites d_out afterwards
    unsigned short* Acvt = (unsigned short*)d_out;

    wt_kernel<<<dim3(32, 32, 3), dim3(32, 8), 0, stream>>>(Wq, Wk, Wv, Wtq, Wtk, Wtv);
    cvt_kernel<<<4096, 256, 0, stream>>>(q, Acvt);
    proj_kernel<<<dim3(64, 8), 256, 0, stream>>>(Acvt, Wtq, Qp, 0);
    cvt_kernel<<<4096, 256, 0, stream>>>(k, Acvt);
    proj_kernel<<<dim3(64, 8), 256, 0, stream>>>(Acvt, Wtk, Kp, 0);
    cvt_kernel<<<4096, 256, 0, stream>>>(v, Acvt);
    proj_kernel<<<dim3(64, 8), 256, 0, stream>>>(Acvt, Wtv, Vtp, 1);
    attn_kernel<<<dim3(8, 64), 256, 0, stream>>>(Qp, Kp, Vtp, vm, qm, out);
}

// Round 3
// 329.754 us; speedup vs baseline: 1.7456x; 1.1103x over previous
//
#include <hip/hip_runtime.h>
#include <hip/hip_bf16.h>

typedef __bf16 bf16x8 __attribute__((ext_vector_type(8)));
typedef float f32x4 __attribute__((ext_vector_type(4)));
typedef unsigned int u32;

#define MFMA16(a, b, c) __builtin_amdgcn_mfma_f32_16x16x32_bf16(a, b, c, 0, 0, 0)

static __device__ __forceinline__ unsigned short f2b(float f) {
    __hip_bfloat16 b = __float2bfloat16(f);
    return __builtin_bit_cast(unsigned short, b);
}
static __device__ __forceinline__ float b2f(unsigned short u) {
    u32 v = ((u32)u) << 16;
    return __builtin_bit_cast(float, v);
}
static __device__ __forceinline__ unsigned short f2b_trunc(float f) {
    return (unsigned short)(__builtin_bit_cast(u32, f) >> 16);
}
static __device__ __forceinline__ void glds16(const void* g, void* l) {
    __builtin_amdgcn_global_load_lds((const __attribute__((address_space(1))) u32*)g,
                                     (__attribute__((address_space(3))) u32*)l, 16, 0, 0);
}

// ---------------- fp32 -> bf16 convert (activations), 8 elems/thread ----------------
__global__ __launch_bounds__(256) void cvt_kernel(const float* __restrict__ src,
                                                  unsigned short* __restrict__ dst) {
    const size_t i = ((size_t)blockIdx.x * 256 + threadIdx.x) * 8;
    float4 a = *(const float4*)(src + i);
    float4 b = *(const float4*)(src + i + 4);
    ushort4 u0 = { f2b(a.x), f2b(a.y), f2b(a.z), f2b(a.w) };
    ushort4 u1 = { f2b(b.x), f2b(b.y), f2b(b.z), f2b(b.w) };
    *(ushort4*)(dst + i) = u0;
    *(ushort4*)(dst + i + 4) = u1;
}

// ---------------- weight transpose + bf16 cast: Wt[n][k] = bf16(W[k][n]) ----------------
__global__ void wt_kernel(const float* __restrict__ W0, const float* __restrict__ W1,
                          const float* __restrict__ W2, unsigned short* __restrict__ T0,
                          unsigned short* __restrict__ T1, unsigned short* __restrict__ T2) {
    const float* W = blockIdx.z == 0 ? W0 : (blockIdx.z == 1 ? W1 : W2);
    unsigned short* T = blockIdx.z == 0 ? T0 : (blockIdx.z == 1 ? T1 : T2);
    __shared__ float tile[32][33];
    const int n0 = blockIdx.x * 32, k0 = blockIdx.y * 32;
    const int tx = threadIdx.x, ty = threadIdx.y;  // block (32, 8)
#pragma unroll
    for (int i = 0; i < 4; i++)
        tile[ty + 8 * i][tx] = W[(size_t)(k0 + ty + 8 * i) * 1024 + n0 + tx];
    __syncthreads();
#pragma unroll
    for (int i = 0; i < 4; i++)
        T[(size_t)(n0 + ty + 8 * i) * 1024 + k0 + tx] = f2b(tile[tx][ty + 8 * i]);
}

// ---------------- projection GEMM (m97-style): dst = bf16(A @ Wt^T) -------------------
// A: [8192][1024] bf16.  Wt: [1024 n][1024 k] bf16.
// vmode 0: dst[(b*16+h)*2048 + s][64] (Q,K)   vmode 1: dst[(b*16+h)*64 + d][2048] (V^T)
// Epilogue: per-wave LDS transpose -> 8B-coalesced stores (512B runs).
__global__ __launch_bounds__(256) void proj_kernel(const unsigned short* __restrict__ A,
        const unsigned short* __restrict__ Wt, unsigned short* __restrict__ dst,
        const int vmode) {
    __shared__ unsigned short smem[17408];   // staging 8192 | epilogue Tw 4 x 64x68
    unsigned short* As = smem;               // [128][32] unpadded (global_load_lds layout)
    unsigned short* Bs = smem + 4096;
    const int m0 = blockIdx.y * 128, n0 = blockIdx.x * 128;  // x = n (8), y = m (64)
    const int tid = threadIdx.x;
    const int w = tid >> 6, lane = tid & 63, quad = lane >> 4, l16 = lane & 15;
    const int wr = (w >> 1) * 64, wc = (w & 1) * 64;
    f32x4 acc[4][4] = {};
    for (int kb = 0; kb < 32; kb++) {
        const int k0 = kb * 32;
        __syncthreads();
#pragma unroll
        for (int i = 0; i < 2; i++) {        // 16B/lane direct-to-LDS DMA
            int idx = tid + i * 256;         // [0,512): row=idx>>2, col8=(idx&3)*8
            int row = idx >> 2, col = (idx & 3) * 8;
            glds16(A + (size_t)(m0 + row) * 1024 + k0 + col, &As[idx * 8]);
            glds16(Wt + (size_t)(n0 + row) * 1024 + k0 + col, &Bs[idx * 8]);
        }
        __syncthreads();
        bf16x8 af[4], bf[4];
#pragma unroll
        for (int mt = 0; mt < 4; mt++) af[mt] = *(const bf16x8*)&As[(wr + mt * 16 + l16) * 32 + quad * 8];
#pragma unroll
        for (int nt = 0; nt < 4; nt++) bf[nt] = *(const bf16x8*)&Bs[(wc + nt * 16 + l16) * 32 + quad * 8];
#pragma unroll
        for (int mt = 0; mt < 4; mt++)
#pragma unroll
            for (int nt = 0; nt < 4; nt++)
                acc[mt][nt] = MFMA16(af[mt], bf[nt], acc[mt][nt]);
    }
    __syncthreads();                         // staging area re-used as transpose buffer
    unsigned short* Tw = smem + w * 4352;    // per-wave 64 x 68
    if (vmode == 0) {                        // rows = tokens, cols = channels
#pragma unroll
        for (int mt = 0; mt < 4; mt++)
#pragma unroll
            for (int nt = 0; nt < 4; nt++)
#pragma unroll
                for (int r = 0; r < 4; r++)
                    Tw[(mt * 16 + quad * 4 + r) * 68 + nt * 16 + l16] = f2b(acc[mt][nt][r]);
    } else {                                 // rows = d, cols = tokens
#pragma unroll
        for (int mt = 0; mt < 4; mt++)
#pragma unroll
            for (int nt = 0; nt < 4; nt++)
#pragma unroll
                for (int r = 0; r < 4; r++)
                    Tw[(nt * 16 + l16) * 68 + mt * 16 + quad * 4 + r] = f2b(acc[mt][nt][r]);
    }
    const int gr0 = m0 + wr, gc0 = n0 + wc;  // wave-private buffer: in-wave order, no barrier
    const int b = gr0 >> 11, s0 = gr0 & 2047, h = gc0 >> 6;
    if (vmode == 0) {
        const size_t obase = (size_t)(b * 16 + h) * 2048;
#pragma unroll
        for (int j = 0; j < 16; j++) {
            int row = j * 4 + quad;          // token offset
            uint2 val = *(const uint2*)&Tw[row * 68 + l16 * 4];
            *(uint2*)(dst + (obase + s0 + row) * 64 + l16 * 4) = val;
        }
    } else {
        const size_t vbase = (size_t)(b * 16 + h) * 64 * 2048;
#pragma unroll
        for (int j = 0; j < 16; j++) {
            int row = j * 4 + quad;          // d
            uint2 val = *(const uint2*)&Tw[row * 68 + l16 * 4];
            *(uint2*)(dst + vbase + (size_t)row * 2048 + s0 + l16 * 4) = val;
        }
    }
}

// ---------------- fused masked-causal flash attention (BQ=64) ----------------
// Qp,Kp: [bh][2048][64] bf16.  Vt: [bh][64][2048] bf16.  out: [b][s][1024] fp32.
// Fixed-max softmax e^(s-8): masked entries underflow to exact 0 (matches the
// reference's fp32 -1e10 absorption). Degenerate rows (all-prefix-masked, l==0)
// get the reference's uniform average via a rare fix-up pass.
// Each block processes q-tiles {x, 31-x}: uniform 33 kv-tile iterations.
__global__ __launch_bounds__(256) void attn_kernel(
        const unsigned short* __restrict__ Qp, const unsigned short* __restrict__ Kp,
        const unsigned short* __restrict__ Vt, const float* __restrict__ vmask,
        const float* __restrict__ qmask, float* __restrict__ out) {
    __shared__ unsigned short Ks[4096];      // [k2][kv 64][32] unpadded panels
    __shared__ unsigned short Vts[4096];     // [k2][d 64][32]
    __shared__ unsigned short Ps[4096];      // [k2][q 64][32] (wave-private rows)
    __shared__ float Vmb[2048];              // precomputed key-mask bias (log2 domain)
    const int bh = blockIdx.y, b = bh >> 4, h = bh & 15;
    const int tid = threadIdx.x;
    const int w = tid >> 6, lane = tid & 63, quad = lane >> 4, l16 = lane & 15;
    const size_t base = (size_t)bh * 2048 * 64;
    const float C1 = 0.18033688f;            // 0.125 * log2(e)
    const float C0 = -11.54156036f;          // -8 * log2(e)
    const float CM = -1.44269504e10f;        // -1e10 * log2(e)
    for (int i = tid; i < 2048; i += 256)
        Vmb[i] = (vmask[b * 2048 + i] != 0.f) ? C0 : (C0 + CM);

    for (int pass = 0; pass < 2; pass++) {
        const int qt = pass ? 31 - blockIdx.x : blockIdx.x;
        const int q0 = qt * 64;
        bf16x8 qa[2];
#pragma unroll
        for (int ks = 0; ks < 2; ks++)
            qa[ks] = *(const bf16x8*)(Qp + base +
                (size_t)(q0 + w * 16 + l16) * 64 + ks * 32 + quad * 8);
        f32x4 o[4] = {};
        float lsum[4] = {};
        const int qrow = q0 + w * 16 + quad * 4;

        for (int kt = 0; kt <= qt; kt++) {
            __syncthreads();                 // prev-iter/prev-pass LDS reads done
#pragma unroll
            for (int i = 0; i < 2; i++) {    // K,V tiles via direct-to-LDS DMA
                int idx = tid + i * 256;     // [0,512): panel=idx>>8, row=(idx>>2)&63
                int chunk = idx & 3, row = (idx >> 2) & 63, panel = idx >> 8;
                glds16(Kp + base + (size_t)(kt * 64 + row) * 64 + panel * 32 + chunk * 8, &Ks[idx * 8]);
                glds16(Vt + base + (size_t)row * 2048 + kt * 64 + panel * 32 + chunk * 8, &Vts[idx * 8]);
            }
            __syncthreads();

            f32x4 s[4];                      // S = Q K^T
#pragma unroll
            for (int nt = 0; nt < 4; nt++) {
                bf16x8 kf0 = *(const bf16x8*)&Ks[(nt * 16 + l16) * 32 + quad * 8];
                bf16x8 kf1 = *(const bf16x8*)&Ks[2048 + (nt * 16 + l16) * 32 + quad * 8];
                f32x4 z = {};
                z = MFMA16(qa[0], kf0, z);
                z = MFMA16(qa[1], kf1, z);
                s[nt] = z;
            }
            // p = 2^(s*C1 + bias); accumulate l; P -> LDS (C-layout -> A-layout)
#pragma unroll
            for (int nt = 0; nt < 4; nt++) {
                const int kv = kt * 64 + nt * 16 + l16;
                const float cb = Vmb[kv];
#pragma unroll
                for (int r = 0; r < 4; r++) {
                    float p = __builtin_amdgcn_exp2f(s[nt][r] * C1 + cb);
                    p = (kv > qrow + r) ? 0.f : p;
                    lsum[r] += p;
                    Ps[(nt >> 1) * 2048 + (w * 16 + quad * 4 + r) * 32 + (nt & 1) * 16 + l16] = f2b_trunc(p);
                }
            }
            // O += P V  (wave-private P rows; in-wave LDS ordering, no barrier)
#pragma unroll
            for (int k2 = 0; k2 < 2; k2++) {
                bf16x8 pa = *(const bf16x8*)&Ps[k2 * 2048 + (w * 16 + l16) * 32 + quad * 8];
#pragma unroll
                for (int dt = 0; dt < 4; dt++) {
                    bf16x8 vb = *(const bf16x8*)&Vts[k2 * 2048 + (dt * 16 + l16) * 32 + quad * 8];
                    o[dt] = MFMA16(pa, vb, o[dt]);
                }
            }
        }
        float l[4];                          // single deferred l reduction (16 col-lanes)
#pragma unroll
        for (int r = 0; r < 4; r++) {
            float t = lsum[r];
#pragma unroll
            for (int off = 1; off < 16; off <<= 1) t += __shfl_xor(t, off);
            l[r] = t;
        }
        // degenerate rows (entire causal prefix v-masked): reference semantics =
        // uniform average over {kv <= q} u {kv > q : vmask==1}
        bool deg = (l[0] == 0.f) | (l[1] == 0.f) | (l[2] == 0.f) | (l[3] == 0.f);
        if (__any((int)deg)) {
#pragma unroll
            for (int r = 0; r < 4; r++)
                if (l[r] == 0.f) {
                    const int qr = qrow + r;
                    float cnt = 0.f;
                    float oacc[4] = {0.f, 0.f, 0.f, 0.f};
                    for (int kv = 0; kv < 2048; kv++) {
                        bool keep = (kv <= qr) || (vmask[b * 2048 + kv] != 0.f);
                        if (keep) {
                            cnt += 1.f;
#pragma unroll
                            for (int dt = 0; dt < 4; dt++)
                                oacc[dt] += b2f(Vt[base + (size_t)(dt * 16 + l16) * 2048 + kv]);
                        }
                    }
                    l[r] = cnt;
#pragma unroll
                    for (int dt = 0; dt < 4; dt++) o[dt][r] = oacc[dt];
                }
        }
#pragma unroll
        for (int r = 0; r < 4; r++) {
            int q = qrow + r;
            float sc = qmask[b * 2048 + q] / l[r];
#pragma unroll
            for (int dt = 0; dt < 4; dt++)
                out[(size_t)(b * 2048 + q) * 1024 + h * 64 + dt * 16 + l16] = o[dt][r] * sc;
        }
    }
}

extern "C" void kernel_launch(void* const* d_in, const int* in_sizes, int n_in,
                              void* d_out, int out_size, void* d_ws, size_t ws_size,
                              hipStream_t stream) {
    const float* q  = (const float*)d_in[0];
    const float* k  = (const float*)d_in[1];
    const float* v  = (const float*)d_in[2];
    const float* vm = (const float*)d_in[3];
    const float* qm = (const float*)d_in[4];
    const float* Wq = (const float*)d_in[5];
    const float* Wk = (const float*)d_in[6];
    const float* Wv = (const float*)d_in[7];
    float* out = (float*)d_out;

    unsigned short* ws  = (unsigned short*)d_ws;
    unsigned short* Wtq = ws;                         // 3 x 1M bf16 (transposed weights)
    unsigned short* Wtk = Wtq + (1u << 20);
    unsigned short* Wtv = Wtk + (1u << 20);
    unsigned short* Qp  = Wtv + (1u << 20);           // 3 x 8M bf16 (projected Q, K, V^T)
    unsigned short* Kp  = Qp + (1u << 23);
    unsigned short* Vtp = Kp + (1u << 23);
    // reuse d_out (32 MB fp32) as the 16 MB bf16 activation-conversion scratch;
    // attn fully overwrites d_out afterwards
    unsigned short* Acvt = (unsigned short*)d_out;

    wt_kernel<<<dim3(32, 32, 3), dim3(32, 8), 0, stream>>>(Wq, Wk, Wv, Wtq, Wtk, Wtv);
    cvt_kernel<<<4096, 256, 0, stream>>>(q, Acvt);
    proj_kernel<<<dim3(8, 64), 256, 0, stream>>>(Acvt, Wtq, Qp, 0);
    cvt_kernel<<<4096, 256, 0, stream>>>(k, Acvt);
    proj_kernel<<<dim3(8, 64), 256, 0, stream>>>(Acvt, Wtk, Kp, 0);
    cvt_kernel<<<4096, 256, 0, stream>>>(v, Acvt);
    proj_kernel<<<dim3(8, 64), 256, 0, stream>>>(Acvt, Wtv, Vtp, 1);
    attn_kernel<<<dim3(16, 64), 256, 0, stream>>>(Qp, Kp, Vtp, vm, qm, out);
}